// Round 12
// baseline (12.995 us; speedup 1.0000x reference)
//
#include <hip/hip_runtime.h>
#include <hip/hip_bf16.h>

// Pooler ragged-mean: out[b,s,:] = mean(features[b, begins[b,s]:ends[b,s], :])
// B=8, T=4096, D=256, S=1024, MAX_W=32. Empty spans -> 0.
//
// R12: fully-queued pipeline (R11 + counted vmcnt, raw barriers).
//   ld begins/ends (oldest: retire w/o draining DMA)
//   issue ALL 10 DMAs/wave (h0 rows 0..95, h1 rows 96..158)
//   discovery (ballot+pack) during flight
//   s_waitcnt vmcnt(4) lgkmcnt(0); raw s_barrier   <- h0 done, h1 in flight
//   consume half-A (rows <= 94, in h0) over h1 flight
//   s_waitcnt vmcnt(0); raw s_barrier
//   consume half-B
// NOTE: __syncthreads() would emit vmcnt(0) before s_barrier and kill the
// overlap — raw __builtin_amdgcn_s_barrier() + manual waits instead.
// XCD pin: batch b = phys&7 -> XCD b.

#define B_DIM 8
#define T_DIM 4096
#define D_DIM 256
#define S_DIM 1024
#define MAX_W 32
#define RWIDTH 128
#define NBLK (B_DIM * (T_DIM / RWIDTH))  // 256 blocks, 1/CU
#define STAGE_ROWS (RWIDTH + MAX_W - 1)  // 159 rows = 159 KB
#define CAP 120                          // per half-list

typedef float vfloat4 __attribute__((ext_vector_type(4)));
typedef const __attribute__((address_space(1))) uint32_t* gptr_t;
typedef __attribute__((address_space(3))) uint32_t* lptr_t;

struct SM {
    float rows[STAGE_ROWS][D_DIM];   // 162816 B
    int cnt[2];                      // 8 B
    unsigned int list[2][CAP];       // 960 B  -> 163784 of 163840 B
};

__global__ __launch_bounds__(1024) void pooler_kernel(
    const float* __restrict__ features,   // [B, T, D]
    const int*   __restrict__ begins,     // [B, S]
    const int*   __restrict__ ends,       // [B, S]
    float*       __restrict__ out)        // [B, S, D]
{
    __shared__ SM sm;

    const int phys = blockIdx.x;
    const int b = phys & 7;          // XCD pin: batch b -> XCD b
    const int r = phys >> 3;         // 0..31 range index
    const int tid  = threadIdx.x;    // 0..1023
    const int wv   = tid >> 6;       // 0..15
    const int lane = tid & 63;

    if (tid < 2) sm.cnt[tid] = 0;
    __syncthreads();                 // nothing outstanding; cheap

    // ---- discovery loads FIRST (oldest vmem -> no DMA drain on use) ----
    const int bg = begins[b * S_DIM + tid];
    const int en = ends[b * S_DIM + tid];

    const int row0  = r * RWIDTH;
    const int nrows = (T_DIM - row0) < STAGE_ROWS ? (T_DIM - row0) : STAGE_ROWS;
    const int rmax  = nrows - 1;
    const float* gbase = features + ((size_t)b * T_DIM + row0) * D_DIM + lane * 4;

    // ---- issue ALL DMAs: 6 h0 + 4 h1 per wave (wave-uniform rows) ----
    #pragma unroll
    for (int k = 0; k < 6; ++k) {
        const int row = wv + k * 16;                 // 0..95 < nrows always
        __builtin_amdgcn_global_load_lds(
            (gptr_t)(gbase + (size_t)row * D_DIM),
            (lptr_t)(&sm.rows[row][0]), 16, 0, 0);
    }
    #pragma unroll
    for (int k = 0; k < 4; ++k) {
        int row = 96 + wv + k * 16;                  // 96..159
        row = row < rmax ? row : rmax;               // clamp: dup same-addr ok
        __builtin_amdgcn_global_load_lds(
            (gptr_t)(gbase + (size_t)row * D_DIM),
            (lptr_t)(&sm.rows[row][0]), 16, 0, 0);
    }

    // ---- discovery during flight: thread t tests span t ----
    {
        const int s = tid;                           // S_DIM == 1024
        int begin = bg > 0 ? bg : 0;
        int end   = en > 0 ? en : 0;
        end = end < T_DIM ? end : T_DIM;
        int w = end - begin;
        w = w < MAX_W ? w : MAX_W;
        w = w > 0 ? w : 0;

        int bgc = begin < (T_DIM - 1) ? begin : (T_DIM - 1);
        const bool pred = (bgc >> 7) == r;
        const int half = (bgc >> 6) & 1;
        const int local = bgc - row0;                // [0,128) when pred

        #pragma unroll
        for (int h = 0; h < 2; ++h) {
            const bool p = pred && (half == h);
            const unsigned long long mask = __ballot(p);
            const int c = __popcll(mask);
            int base = 0;
            if (lane == 0 && c) base = atomicAdd(&sm.cnt[h], c);
            base = __shfl(base, 0);
            if (p) {
                const int pos = base + __popcll(mask & ((1ULL << lane) - 1ULL));
                if (pos < CAP) {
                    sm.list[h][pos] =
                        (unsigned int)s | ((unsigned int)local << 10)
                                        | ((unsigned int)w << 17);
                } else {
                    // overflow fallback (never hit for benchmark data)
                    float* op = out + (size_t)(b * S_DIM + s) * D_DIM;
                    if (w <= 0) {
                        for (int d = 0; d < D_DIM; ++d) op[d] = 0.f;
                    } else {
                        const float* fp =
                            features + ((size_t)b * T_DIM + begin) * D_DIM;
                        const float inv = 1.0f / (float)w;
                        for (int d = 0; d < D_DIM; ++d) {
                            float a = 0.f;
                            for (int j = 0; j < w; ++j)
                                a += fp[(size_t)j * D_DIM + d];
                            op[d] = a * inv;
                        }
                    }
                }
            }
        }
    }

    // ---- h0 complete (4 h1 still in flight) + LDS lists visible ----
    asm volatile("s_waitcnt vmcnt(4) lgkmcnt(0)" ::: "memory");
    __builtin_amdgcn_s_barrier();
    __builtin_amdgcn_sched_barrier(0);

    // ---- consume half A (rows <= 94, all in h0) over h1 flight ----
    const int cntA = sm.cnt[0] < CAP ? sm.cnt[0] : CAP;
    for (int i = wv; i < cntA; i += 16) {
        const unsigned int e = sm.list[0][i];
        const int s     = e & 1023;
        const int local = (e >> 10) & 127;
        const int w     = (e >> 17) & 63;

        vfloat4* outp = reinterpret_cast<vfloat4*>(
            out + (size_t)(b * S_DIM + s) * D_DIM) + lane;
        if (w == 0) {
            vfloat4 z = {0.f, 0.f, 0.f, 0.f};
            __builtin_nontemporal_store(z, outp);
            continue;
        }
        const vfloat4* lp =
            reinterpret_cast<const vfloat4*>(&sm.rows[local][0]) + lane;
        vfloat4 acc = {0.f, 0.f, 0.f, 0.f};
        #pragma unroll 8
        for (int j = 0; j < w; ++j) acc += lp[(size_t)j * (D_DIM / 4)];
        const float inv = 1.0f / (float)w;
        vfloat4 res = acc * inv;
        __builtin_nontemporal_store(res, outp);
    }

    // ---- h1 complete ----
    asm volatile("s_waitcnt vmcnt(0)" ::: "memory");
    __builtin_amdgcn_s_barrier();
    __builtin_amdgcn_sched_barrier(0);

    // ---- consume half B (rows 64..158, fully staged) ----
    const int cntB = sm.cnt[1] < CAP ? sm.cnt[1] : CAP;
    for (int i = wv; i < cntB; i += 16) {
        const unsigned int e = sm.list[1][i];
        const int s     = e & 1023;
        const int local = (e >> 10) & 127;
        const int w     = (e >> 17) & 63;

        vfloat4* outp = reinterpret_cast<vfloat4*>(
            out + (size_t)(b * S_DIM + s) * D_DIM) + lane;
        if (w == 0) {
            vfloat4 z = {0.f, 0.f, 0.f, 0.f};
            __builtin_nontemporal_store(z, outp);
            continue;
        }
        const vfloat4* lp =
            reinterpret_cast<const vfloat4*>(&sm.rows[local][0]) + lane;
        vfloat4 acc = {0.f, 0.f, 0.f, 0.f};
        #pragma unroll 8
        for (int j = 0; j < w; ++j) acc += lp[(size_t)j * (D_DIM / 4)];
        const float inv = 1.0f / (float)w;
        vfloat4 res = acc * inv;
        __builtin_nontemporal_store(res, outp);
    }
}

extern "C" void kernel_launch(void* const* d_in, const int* in_sizes, int n_in,
                              void* d_out, int out_size, void* d_ws, size_t ws_size,
                              hipStream_t stream) {
    const float* features = (const float*)d_in[0];
    const int*   begins   = (const int*)d_in[1];
    const int*   ends     = (const int*)d_in[2];
    float*       out      = (float*)d_out;

    pooler_kernel<<<NBLK, 1024, 0, stream>>>(features, begins, ends, out);
}